// Round 1
// baseline (499.518 us; speedup 1.0000x reference)
//
#include <hip/hip_runtime.h>

#define NPI    33600     // anchors per image: 160^2 + 80^2 + 40^2
#define KTOP   500
#define CAP    1024
#define KEY001 0xBC23D70Au   // monotonic key of 0.01f
#define NBINS  65536
#define NGRP   1024

__device__ __forceinline__ float sigmoidf_(float x) {
  return 1.0f / (1.0f + expf(-x));
}
// monotonic float -> u32 key (order-preserving for all non-NaN floats)
__device__ __forceinline__ unsigned fkey(float f) {
  unsigned u = __float_as_uint(f);
  return (u & 0x80000000u) ? ~u : (u | 0x80000000u);
}

// ---------------- Kernel 1: score + key + histograms ----------------
// thread = 4 consecutive anchors (float4 coalesced channel reads)
__global__ __launch_bounds__(256) void k_score(
    const float* __restrict__ p8, const float* __restrict__ p16,
    const float* __restrict__ p32,
    unsigned* __restrict__ hist, unsigned* __restrict__ hist2,
    unsigned* __restrict__ keys)
{
  const int b = blockIdx.y;
  const int t = blockIdx.x * 256 + threadIdx.x;
  const int a = t * 4;
  if (a >= NPI) return;
  const float* lvl; int j, HW;
  if (a < 25600)      { lvl = p8;  j = a;         HW = 25600; }
  else if (a < 32000) { lvl = p16; j = a - 25600; HW = 6400;  }
  else                { lvl = p32; j = a - 32000; HW = 1600;  }
  const float* base = lvl + (size_t)b * 85 * HW + j;
  float4 o4 = *(const float4*)(base + 4 * HW);
  float m0 = -INFINITY, m1 = -INFINITY, m2 = -INFINITY, m3 = -INFINITY;
  #pragma unroll 8
  for (int c = 0; c < 80; ++c) {
    float4 v = *(const float4*)(base + (size_t)(5 + c) * HW);
    m0 = fmaxf(m0, v.x); m1 = fmaxf(m1, v.y);
    m2 = fmaxf(m2, v.z); m3 = fmaxf(m3, v.w);
  }
  float ov[4] = {o4.x, o4.y, o4.z, o4.w};
  float mv[4] = {m0, m1, m2, m3};
  unsigned k4[4];
  #pragma unroll
  for (int e = 0; e < 4; ++e) {
    // max(sigmoid(cls)) == sigmoid(max(cls)) (monotone), argmax not needed here
    float tot = sigmoidf_(ov[e]) * sigmoidf_(mv[e]);
    float masked = (tot >= 0.01f) ? tot : -1.0f;
    k4[e] = fkey(masked);
  }
  *(uint4*)(keys + (size_t)b * NPI + a) = make_uint4(k4[0], k4[1], k4[2], k4[3]);
  unsigned* hb = hist  + (size_t)b * NBINS;
  unsigned* gb = hist2 + (size_t)b * NGRP;
  #pragma unroll
  for (int e = 0; e < 4; ++e) {
    atomicAdd(&hb[k4[e] >> 16], 1u);
    atomicAdd(&gb[k4[e] >> 22], 1u);
  }
}

// full decode of one anchor (exact per-class sigmoid argmax, first-occurrence)
__device__ void decode_one(const float* __restrict__ p8, const float* __restrict__ p16,
                           const float* __restrict__ p32, int b, int a, float det[7])
{
  const float* lvl; int j, W, HW, S;
  if (a < 25600)      { lvl = p8;  j = a;         W = 160; HW = 25600; S = 8;  }
  else if (a < 32000) { lvl = p16; j = a - 25600; W = 80;  HW = 6400;  S = 16; }
  else                { lvl = p32; j = a - 32000; W = 40;  HW = 1600;  S = 32; }
  const float* base = lvl + (size_t)b * 85 * HW + j;
  float t0 = base[0];
  float t1 = base[(size_t)1 * HW];
  float t2 = base[(size_t)2 * HW];
  float t3 = base[(size_t)3 * HW];
  float t4 = base[(size_t)4 * HW];
  int gy = j / W, gx = j - gy * W;
  float fs = (float)S;
  float cx = (t0 + (float)gx) * fs;
  float cy = (t1 + (float)gy) * fs;
  float w  = expf(t2) * fs;
  float h  = expf(t3) * fs;
  float obj = sigmoidf_(t4);
  float cc = -1.0f; int lab = 0;
  for (int c = 0; c < 80; ++c) {
    float s = sigmoidf_(base[(size_t)(5 + c) * HW]);
    if (s > cc) { cc = s; lab = c; }   // strict > : first occurrence wins (jnp.argmax)
  }
  det[0] = cx - w * 0.5f; det[1] = cy - h * 0.5f;
  det[2] = cx + w * 0.5f; det[3] = cy + h * 0.5f;
  det[4] = obj; det[5] = cc; det[6] = (float)lab;
}

// ---------------- Kernel 2: per-image select + sort + NMS + write ----------------
__global__ __launch_bounds__(1024) void k_post(
    const float* __restrict__ p8, const float* __restrict__ p16,
    const float* __restrict__ p32,
    const unsigned* __restrict__ hist, const unsigned* __restrict__ hist2,
    const unsigned* __restrict__ keys, float* __restrict__ out)
{
  const int b   = blockIdx.x;
  const int tid = threadIdx.x;
  const int lane = tid & 63;
  const int wave = tid >> 6;

  __shared__ unsigned sh_ps[NGRP];
  __shared__ unsigned sh_T, sh_Chi;
  __shared__ unsigned sh_nA, sh_nB;
  __shared__ unsigned long long sh_cand[CAP];
  __shared__ float sh_det[KTOP][7];
  __shared__ float sh_box[KTOP][4];
  __shared__ unsigned sh_mask[KTOP * 16];
  __shared__ unsigned sh_inval[16];
  __shared__ unsigned sh_keep[16];
  __shared__ unsigned sh_wcA[16], sh_wcB[16];
  __shared__ float sh_red[16];
  __shared__ float sh_maxc;

  // ---- Phase A: find threshold bin T (500th value), C_hi = count above bin T
  sh_ps[tid] = hist2[(size_t)b * NGRP + tid];
  __syncthreads();
  if (tid == 0) {
    unsigned cum = 0, cumAfter = 0; int G = NGRP - 1;
    for (int g = NGRP - 1; g >= 0; --g) {
      unsigned v = sh_ps[g];
      if (cum + v >= KTOP) { G = g; cumAfter = cum; break; }
      cum += v;
    }
    const unsigned* hb = hist + (size_t)b * NBINS;
    unsigned c = cumAfter, T = (unsigned)G * 64u, Chi = cumAfter;
    for (int t2 = G * 64 + 63; t2 >= G * 64; --t2) {
      unsigned hv = hb[t2];
      if (c + hv >= KTOP) { T = (unsigned)t2; Chi = c; break; }
      c += hv;
    }
    sh_T = T; sh_Chi = Chi; sh_nA = 0; sh_nB = 0;
  }
  __syncthreads();
  const unsigned T = sh_T, Chi = sh_Chi;
  const unsigned Bcap = CAP - Chi;

  // ---- Phase B: deterministic (index-ordered) compaction of candidates
  // A: bin > T -> definitely in top-500, appended from the front.
  // B: bin == T -> boundary bin, appended from the back, lowest indices kept.
  const unsigned* kb = keys + (size_t)b * NPI;
  for (int chunk = 0; chunk < 9; ++chunk) {
    int a0 = chunk * 4096 + tid * 4;
    unsigned kk[4]; bool iA[4], iB[4];
    bool act = (a0 < NPI);
    if (act) {
      uint4 kv = *(const uint4*)(kb + a0);
      kk[0] = kv.x; kk[1] = kv.y; kk[2] = kv.z; kk[3] = kv.w;
    } else { kk[0] = kk[1] = kk[2] = kk[3] = 0u; }
    #pragma unroll
    for (int e = 0; e < 4; ++e) {
      unsigned bin = kk[e] >> 16;
      iA[e] = act && (bin > T);
      iB[e] = act && (bin == T);
    }
    unsigned long long balA[4], balB[4];
    #pragma unroll
    for (int e = 0; e < 4; ++e) { balA[e] = __ballot(iA[e]); balB[e] = __ballot(iB[e]); }
    if (lane == 0) {
      unsigned sA = 0, sB = 0;
      #pragma unroll
      for (int e = 0; e < 4; ++e) { sA += (unsigned)__popcll(balA[e]); sB += (unsigned)__popcll(balB[e]); }
      sh_wcA[wave] = sA; sh_wcB[wave] = sB;
    }
    __syncthreads();
    unsigned pA = sh_nA, pB = sh_nB;
    for (int w2 = 0; w2 < wave; ++w2) { pA += sh_wcA[w2]; pB += sh_wcB[w2]; }
    unsigned long long lt = (1ULL << lane) - 1ULL;
    #pragma unroll
    for (int e = 0; e < 4; ++e) {
      pA += (unsigned)__popcll(balA[e] & lt);
      pB += (unsigned)__popcll(balB[e] & lt);
    }
    #pragma unroll
    for (int e = 0; e < 4; ++e) {
      unsigned long long packed =
          ((unsigned long long)kk[e] << 32) |
          (unsigned long long)(0xFFFFFFFFu - (unsigned)(a0 + e));
      if (iA[e]) { sh_cand[pA] = packed; ++pA; }
      if (iB[e]) { if (pB < Bcap) sh_cand[CAP - 1 - pB] = packed; ++pB; }
    }
    __syncthreads();
    if (tid == 0) {
      unsigned sA = 0, sB = 0;
      for (int w2 = 0; w2 < 16; ++w2) { sA += sh_wcA[w2]; sB += sh_wcB[w2]; }
      sh_nA += sA; sh_nB += sB;
    }
    __syncthreads();
  }
  {
    const unsigned nA  = sh_nA;
    const unsigned nBk = (sh_nB < Bcap) ? sh_nB : Bcap;
    for (int s = (int)nA + tid; s < (int)(CAP - nBk); s += 1024) sh_cand[s] = 0ULL;
  }
  __syncthreads();

  // ---- Phase C: bitonic sort 1024 u64 descending ((score desc, index asc))
  for (unsigned kk2 = 2; kk2 <= CAP; kk2 <<= 1) {
    for (unsigned jj = kk2 >> 1; jj > 0; jj >>= 1) {
      unsigned i = (unsigned)tid, p = i ^ jj;
      if (p > i) {
        unsigned long long x = sh_cand[i], y = sh_cand[p];
        bool desc = ((i & kk2) == 0);
        if ((x < y) == desc) { sh_cand[i] = y; sh_cand[p] = x; }
      }
      __syncthreads();
    }
  }

  // ---- Phase D: decode top-500, max_c, offset boxes, invalid bitset
  bool validk = false;
  float contrib = -INFINITY;
  if (tid < KTOP) {
    unsigned long long v = sh_cand[tid];
    unsigned keyk = (unsigned)(v >> 32);
    int a = (int)(0xFFFFFFFFu - (unsigned)(v & 0xFFFFFFFFull));
    float det[7];
    decode_one(p8, p16, p32, b, a, det);
    #pragma unroll
    for (int c = 0; c < 7; ++c) sh_det[tid][c] = det[c];
    validk = (keyk >= KEY001);
    float m4 = fmaxf(fmaxf(det[0], det[1]), fmaxf(det[2], det[3]));
    contrib = validk ? m4 : 0.0f;   // jnp.where(valid, boxes, 0) then global max
  }
  float r = contrib;
  #pragma unroll
  for (int off = 32; off > 0; off >>= 1) r = fmaxf(r, __shfl_xor(r, off));
  if (lane == 0) sh_red[wave] = r;
  unsigned long long bv = __ballot((tid < KTOP) && !validk);
  if (wave < 8 && lane == 0) {
    sh_inval[wave * 2]     = (unsigned)(bv & 0xFFFFFFFFull);
    sh_inval[wave * 2 + 1] = (unsigned)(bv >> 32);
  }
  __syncthreads();
  if (tid == 0) {
    float m = -INFINITY;
    for (int w2 = 0; w2 < 16; ++w2) m = fmaxf(m, sh_red[w2]);
    sh_maxc = m + 1.0f;
  }
  __syncthreads();
  const float maxc = sh_maxc;
  if (tid < KTOP) {
    float offb = sh_det[tid][6] * maxc;   // label * max_c
    #pragma unroll
    for (int d = 0; d < 4; ++d) sh_box[tid][d] = sh_det[tid][d] + offb;
  }
  __syncthreads();

  // ---- Phase E: IoU suppression bitmask (upper triangle), fully parallel
  // task = w*KTOP + i so a wave's lanes share w -> sh_box[j] reads broadcast
  for (int task = tid; task < KTOP * 16; task += 1024) {
    int i = task % KTOP;
    int w = task / KTOP;
    int jbase = w * 32;
    unsigned bits = 0u;
    if (jbase + 31 > i) {
      float ix1 = sh_box[i][0], iy1 = sh_box[i][1], ix2 = sh_box[i][2], iy2 = sh_box[i][3];
      float a1 = fmaxf(ix2 - ix1, 0.0f) * fmaxf(iy2 - iy1, 0.0f);
      #pragma unroll 4
      for (int jj = 0; jj < 32; ++jj) {
        int j = jbase + jj;
        if (j < KTOP && j > i) {
          float jx1 = sh_box[j][0], jy1 = sh_box[j][1];
          float jx2 = sh_box[j][2], jy2 = sh_box[j][3];
          float iw = fminf(ix2, jx2) - fmaxf(ix1, jx1);
          float ih = fminf(iy2, jy2) - fmaxf(iy1, jy1);
          float inter = fmaxf(iw, 0.0f) * fmaxf(ih, 0.0f);
          float a2 = fmaxf(jx2 - jx1, 0.0f) * fmaxf(jy2 - jy1, 0.0f);
          // iou > 0.65  <=>  inter > 0.65*(a1+a2-inter+1e-9)
          if (inter > 0.65f * (a1 + a2 - inter + 1e-9f)) bits |= (1u << jj);
        }
      }
    }
    sh_mask[i * 16 + w] = bits;
  }
  __syncthreads();

  // ---- Phase F: greedy sequential scan (wave 0); lane l<16 owns suppressed word l
  if (tid < 64) {
    unsigned sup   = (lane < 16) ? sh_inval[lane] : 0u;
    unsigned keepw = 0u;
    unsigned cur = (unsigned)__builtin_amdgcn_readlane((int)sup, 0);
    unsigned mA = (lane < 16) ? sh_mask[0 * 16 + lane] : 0u;
    unsigned mB = (lane < 16) ? sh_mask[1 * 16 + lane] : 0u;
    for (int i = 0; i < KTOP; i += 2) {
      bool ok = ((cur >> (i & 31)) & 1u) == 0u;
      if (ok) {
        sup |= mA;
        if (lane == (i >> 5)) keepw |= (1u << (i & 31));
      }
      cur = (unsigned)__builtin_amdgcn_readlane((int)sup, (i + 1) >> 5);
      mA = (lane < 16 && (i + 2) < KTOP) ? sh_mask[(i + 2) * 16 + lane] : 0u;
      bool ok2 = ((cur >> ((i + 1) & 31)) & 1u) == 0u;
      if (ok2) {
        sup |= mB;
        if (lane == ((i + 1) >> 5)) keepw |= (1u << ((i + 1) & 31));
      }
      cur = (unsigned)__builtin_amdgcn_readlane((int)sup, (i + 2) >> 5);
      mB = (lane < 16 && (i + 3) < KTOP) ? sh_mask[(i + 3) * 16 + lane] : 0u;
    }
    if (lane < 16) sh_keep[lane] = keepw;
  }
  __syncthreads();

  // ---- Phase G: write det * keep
  for (int x = tid; x < KTOP * 7; x += 1024) {
    int k = x / 7, c = x - k * 7;
    float keepf = ((sh_keep[k >> 5] >> (k & 31)) & 1u) ? 1.0f : 0.0f;
    out[(size_t)b * (KTOP * 7) + x] = sh_det[k][c] * keepf;
  }
}

extern "C" void kernel_launch(void* const* d_in, const int* in_sizes, int n_in,
                              void* d_out, int out_size, void* d_ws, size_t ws_size,
                              hipStream_t stream) {
  const float* p8  = (const float*)d_in[0];
  const float* p16 = (const float*)d_in[1];
  const float* p32 = (const float*)d_in[2];
  float* out = (float*)d_out;
  unsigned* hist  = (unsigned*)d_ws;          // [8][65536]
  unsigned* hist2 = hist + 8 * NBINS;         // [8][1024]
  unsigned* keys  = hist2 + 8 * NGRP;         // [8][33600]
  size_t zero_bytes = (size_t)8 * NBINS * 4 + (size_t)8 * NGRP * 4;
  hipMemsetAsync(d_ws, 0, zero_bytes, stream);
  k_score<<<dim3(33, 8), 256, 0, stream>>>(p8, p16, p32, hist, hist2, keys);
  k_post<<<dim3(8), 1024, 0, stream>>>(p8, p16, p32, hist, hist2, keys, out);
}

// Round 2
// 267.076 us; speedup vs baseline: 1.8703x; 1.8703x over previous
//
#include <hip/hip_runtime.h>

#define NPI    33600     // anchors per image: 160^2 + 80^2 + 40^2
#define KTOP   500
#define CAP    1024
#define KEY001 0xBC23D70Au   // monotonic key of 0.01f
#define NGRP   1024

__device__ __forceinline__ float sigmoidf_(float x) {
  return 1.0f / (1.0f + expf(-x));
}
// monotonic float -> u32 key (order-preserving for all non-NaN floats)
__device__ __forceinline__ unsigned fkey(float f) {
  unsigned u = __float_as_uint(f);
  return (u & 0x80000000u) ? ~u : (u | 0x80000000u);
}

// ---------------- Kernel 1: score + key + LDS-aggregated coarse histogram ----------
// thread = 2 consecutive anchors (float2 coalesced channel reads, 8-deep load ILP)
__global__ __launch_bounds__(256) void k_score(
    const float* __restrict__ p8, const float* __restrict__ p16,
    const float* __restrict__ p32,
    unsigned* __restrict__ hist2, unsigned* __restrict__ keys)
{
  const int b = blockIdx.y;
  const int t = blockIdx.x * 256 + threadIdx.x;
  const int a = t * 2;
  __shared__ unsigned lh[NGRP];
  for (int i = threadIdx.x; i < NGRP; i += 256) lh[i] = 0;
  __syncthreads();

  const bool act = (a < NPI);
  if (act) {
    const float* lvl; int j, HW;
    if (a < 25600)      { lvl = p8;  j = a;         HW = 25600; }
    else if (a < 32000) { lvl = p16; j = a - 25600; HW = 6400;  }
    else                { lvl = p32; j = a - 32000; HW = 1600;  }
    const float* base = lvl + (size_t)b * 85 * HW + j;
    float2 o2 = *(const float2*)(base + 4 * HW);
    float m0 = -INFINITY, m1 = -INFINITY;
    for (int cc = 0; cc < 80; cc += 8) {
      float2 v[8];
      #pragma unroll
      for (int u = 0; u < 8; ++u)
        v[u] = *(const float2*)(base + (size_t)(5 + cc + u) * HW);
      #pragma unroll
      for (int u = 0; u < 8; ++u) { m0 = fmaxf(m0, v[u].x); m1 = fmaxf(m1, v[u].y); }
    }
    // max(sigmoid(cls)) == sigmoid(max(cls)) (monotone) — identical math to passing version
    float t0 = sigmoidf_(o2.x) * sigmoidf_(m0);
    float t1 = sigmoidf_(o2.y) * sigmoidf_(m1);
    unsigned k0 = fkey(t0 >= 0.01f ? t0 : -1.0f);
    unsigned k1 = fkey(t1 >= 0.01f ? t1 : -1.0f);
    *(uint2*)(keys + (size_t)b * NPI + a) = make_uint2(k0, k1);
    atomicAdd(&lh[k0 >> 22], 1u);
    atomicAdd(&lh[k1 >> 22], 1u);
  }
  __syncthreads();
  unsigned* gb = hist2 + (size_t)b * NGRP;
  for (int i = threadIdx.x; i < NGRP; i += 256) {
    unsigned v = lh[i];
    if (v) atomicAdd(&gb[i], v);
  }
}

// full decode of one anchor (exact per-class sigmoid argmax, first-occurrence)
__device__ void decode_one(const float* __restrict__ p8, const float* __restrict__ p16,
                           const float* __restrict__ p32, int b, int a, float det[7])
{
  const float* lvl; int j, W, HW, S;
  if (a < 25600)      { lvl = p8;  j = a;         W = 160; HW = 25600; S = 8;  }
  else if (a < 32000) { lvl = p16; j = a - 25600; W = 80;  HW = 6400;  S = 16; }
  else                { lvl = p32; j = a - 32000; W = 40;  HW = 1600;  S = 32; }
  const float* base = lvl + (size_t)b * 85 * HW + j;
  float t0 = base[0];
  float t1 = base[(size_t)1 * HW];
  float t2 = base[(size_t)2 * HW];
  float t3 = base[(size_t)3 * HW];
  float t4 = base[(size_t)4 * HW];
  int gy = j / W, gx = j - gy * W;
  float fs = (float)S;
  float cx = (t0 + (float)gx) * fs;
  float cy = (t1 + (float)gy) * fs;
  float w  = expf(t2) * fs;
  float h  = expf(t3) * fs;
  float obj = sigmoidf_(t4);
  float cc = -1.0f; int lab = 0;
  for (int c = 0; c < 80; ++c) {
    float s = sigmoidf_(base[(size_t)(5 + c) * HW]);
    if (s > cc) { cc = s; lab = c; }   // strict > : first occurrence wins (jnp.argmax)
  }
  det[0] = cx - w * 0.5f; det[1] = cy - h * 0.5f;
  det[2] = cx + w * 0.5f; det[3] = cy + h * 0.5f;
  det[4] = obj; det[5] = cc; det[6] = (float)lab;
}

// ---------------- Kernel 2: per-image select + sort + NMS + write ----------------
__global__ __launch_bounds__(1024) void k_post(
    const float* __restrict__ p8, const float* __restrict__ p16,
    const float* __restrict__ p32,
    const unsigned* __restrict__ hist2,
    const unsigned* __restrict__ keys, float* __restrict__ out)
{
  const int b   = blockIdx.x;
  const int tid = threadIdx.x;
  const int lane = tid & 63;
  const int wave = tid >> 6;

  __shared__ unsigned sh_ps[NGRP];       // 4 KB
  __shared__ unsigned sh_sub[4096];      // 16 KB
  __shared__ unsigned sh_c64[64];
  __shared__ unsigned sh_G, sh_Chi10;
  __shared__ unsigned sh_T, sh_Chi;
  __shared__ unsigned sh_nA, sh_nB;
  __shared__ unsigned long long sh_cand[CAP];
  __shared__ float sh_det[KTOP][7];
  __shared__ float sh_box[KTOP][4];
  __shared__ unsigned sh_mask[KTOP * 16];
  __shared__ unsigned sh_inval[16];
  __shared__ unsigned sh_keep[16];
  __shared__ unsigned sh_wcA[16], sh_wcB[16];
  __shared__ float sh_red[16];
  __shared__ float sh_maxc;

  // ---- Phase A1: find boundary 10-bit group G from coarse histogram
  sh_ps[tid] = hist2[(size_t)b * NGRP + tid];
  for (int i = tid; i < 4096; i += 1024) sh_sub[i] = 0;
  __syncthreads();
  if (tid < 64) {
    unsigned s = 0;
    #pragma unroll
    for (int k = 0; k < 16; ++k) s += sh_ps[tid * 16 + k];
    sh_c64[tid] = s;
  }
  __syncthreads();
  if (tid == 0) {
    unsigned cum = 0; int C = 0;
    for (int g = 63; g >= 0; --g) {
      unsigned v = sh_c64[g];
      if (cum + v >= KTOP) { C = g; break; }
      cum += v;
    }
    int G = C * 16; unsigned chi = cum;
    for (int g = C * 16 + 15; g >= C * 16; --g) {
      unsigned v = sh_ps[g];
      if (chi + v >= KTOP) { G = g; break; }
      chi += v;
    }
    sh_G = (unsigned)G; sh_Chi10 = chi;
    sh_nA = 0; sh_nB = 0;
  }
  __syncthreads();
  const unsigned G = sh_G;

  // ---- Phase A2: refinement pass — 4096-bin sub-hist of bits [21:10] within group G
  const unsigned* kb = keys + (size_t)b * NPI;
  for (int i = tid; i < NPI; i += 1024) {
    unsigned k = kb[i];
    if ((k >> 22) == G) atomicAdd(&sh_sub[(k >> 10) & 4095u], 1u);
  }
  __syncthreads();
  if (tid < 64) {
    unsigned s = 0;
    for (int k = 0; k < 64; ++k) s += sh_sub[tid * 64 + k];
    sh_c64[tid] = s;
  }
  __syncthreads();
  if (tid == 0) {
    unsigned c = sh_Chi10; int C2 = 0;
    for (int g = 63; g >= 0; --g) {
      unsigned v = sh_c64[g];
      if (c + v >= KTOP) { C2 = g; break; }
      c += v;
    }
    int T12 = C2 * 64;
    for (int t2 = C2 * 64 + 63; t2 >= C2 * 64; --t2) {
      unsigned v = sh_sub[t2];
      if (c + v >= KTOP) { T12 = t2; break; }
      c += v;
    }
    sh_T = (G << 12) | (unsigned)T12;   // 22-bit threshold
    sh_Chi = c;
  }
  __syncthreads();
  const unsigned T = sh_T, Chi = sh_Chi;
  const unsigned Bcap = CAP - Chi;

  // ---- Phase B: deterministic (index-ordered) compaction of candidates
  // A: 22-bit prefix > T -> definitely in top-500, appended from the front.
  // B: prefix == T -> boundary bin, appended from the back, lowest indices kept.
  for (int chunk = 0; chunk < 9; ++chunk) {
    int a0 = chunk * 4096 + tid * 4;
    unsigned kk[4]; bool iA[4], iB[4];
    bool act = (a0 < NPI);
    if (act) {
      uint4 kv = *(const uint4*)(kb + a0);
      kk[0] = kv.x; kk[1] = kv.y; kk[2] = kv.z; kk[3] = kv.w;
    } else { kk[0] = kk[1] = kk[2] = kk[3] = 0u; }
    #pragma unroll
    for (int e = 0; e < 4; ++e) {
      unsigned bin = kk[e] >> 10;
      iA[e] = act && (bin > T);
      iB[e] = act && (bin == T);
    }
    unsigned long long balA[4], balB[4];
    #pragma unroll
    for (int e = 0; e < 4; ++e) { balA[e] = __ballot(iA[e]); balB[e] = __ballot(iB[e]); }
    if (lane == 0) {
      unsigned sA = 0, sB = 0;
      #pragma unroll
      for (int e = 0; e < 4; ++e) { sA += (unsigned)__popcll(balA[e]); sB += (unsigned)__popcll(balB[e]); }
      sh_wcA[wave] = sA; sh_wcB[wave] = sB;
    }
    __syncthreads();
    unsigned pA = sh_nA, pB = sh_nB;
    for (int w2 = 0; w2 < wave; ++w2) { pA += sh_wcA[w2]; pB += sh_wcB[w2]; }
    unsigned long long lt = (1ULL << lane) - 1ULL;
    #pragma unroll
    for (int e = 0; e < 4; ++e) {
      pA += (unsigned)__popcll(balA[e] & lt);
      pB += (unsigned)__popcll(balB[e] & lt);
    }
    #pragma unroll
    for (int e = 0; e < 4; ++e) {
      unsigned long long packed =
          ((unsigned long long)kk[e] << 32) |
          (unsigned long long)(0xFFFFFFFFu - (unsigned)(a0 + e));
      if (iA[e]) { sh_cand[pA] = packed; ++pA; }
      if (iB[e]) { if (pB < Bcap) sh_cand[CAP - 1 - pB] = packed; ++pB; }
    }
    __syncthreads();
    if (tid == 0) {
      unsigned sA = 0, sB = 0;
      for (int w2 = 0; w2 < 16; ++w2) { sA += sh_wcA[w2]; sB += sh_wcB[w2]; }
      sh_nA += sA; sh_nB += sB;
    }
    __syncthreads();
  }
  {
    const unsigned nA  = sh_nA;
    const unsigned nBk = (sh_nB < Bcap) ? sh_nB : Bcap;
    for (int s = (int)nA + tid; s < (int)(CAP - nBk); s += 1024) sh_cand[s] = 0ULL;
  }
  __syncthreads();

  // ---- Phase C: bitonic sort 1024 u64 descending ((score desc, index asc))
  for (unsigned kk2 = 2; kk2 <= CAP; kk2 <<= 1) {
    for (unsigned jj = kk2 >> 1; jj > 0; jj >>= 1) {
      unsigned i = (unsigned)tid, p = i ^ jj;
      if (p > i) {
        unsigned long long x = sh_cand[i], y = sh_cand[p];
        bool desc = ((i & kk2) == 0);
        if ((x < y) == desc) { sh_cand[i] = y; sh_cand[p] = x; }
      }
      __syncthreads();
    }
  }

  // ---- Phase D: decode top-500, max_c, offset boxes, invalid bitset
  bool validk = false;
  float contrib = -INFINITY;
  if (tid < KTOP) {
    unsigned long long v = sh_cand[tid];
    unsigned keyk = (unsigned)(v >> 32);
    int a = (int)(0xFFFFFFFFu - (unsigned)(v & 0xFFFFFFFFull));
    float det[7];
    decode_one(p8, p16, p32, b, a, det);
    #pragma unroll
    for (int c = 0; c < 7; ++c) sh_det[tid][c] = det[c];
    validk = (keyk >= KEY001);
    float m4 = fmaxf(fmaxf(det[0], det[1]), fmaxf(det[2], det[3]));
    contrib = validk ? m4 : 0.0f;   // jnp.where(valid, boxes, 0) then global max
  }
  float r = contrib;
  #pragma unroll
  for (int off = 32; off > 0; off >>= 1) r = fmaxf(r, __shfl_xor(r, off));
  if (lane == 0) sh_red[wave] = r;
  unsigned long long bv = __ballot((tid < KTOP) && !validk);
  if (wave < 8 && lane == 0) {
    sh_inval[wave * 2]     = (unsigned)(bv & 0xFFFFFFFFull);
    sh_inval[wave * 2 + 1] = (unsigned)(bv >> 32);
  }
  __syncthreads();
  if (tid == 0) {
    float m = -INFINITY;
    for (int w2 = 0; w2 < 16; ++w2) m = fmaxf(m, sh_red[w2]);
    sh_maxc = m + 1.0f;
  }
  __syncthreads();
  const float maxc = sh_maxc;
  if (tid < KTOP) {
    float offb = sh_det[tid][6] * maxc;   // label * max_c
    #pragma unroll
    for (int d = 0; d < 4; ++d) sh_box[tid][d] = sh_det[tid][d] + offb;
  }
  __syncthreads();

  // ---- Phase E: IoU suppression bitmask (upper triangle), fully parallel
  for (int task = tid; task < KTOP * 16; task += 1024) {
    int i = task % KTOP;
    int w = task / KTOP;
    int jbase = w * 32;
    unsigned bits = 0u;
    if (jbase + 31 > i) {
      float ix1 = sh_box[i][0], iy1 = sh_box[i][1], ix2 = sh_box[i][2], iy2 = sh_box[i][3];
      float a1 = fmaxf(ix2 - ix1, 0.0f) * fmaxf(iy2 - iy1, 0.0f);
      #pragma unroll 4
      for (int jj = 0; jj < 32; ++jj) {
        int j = jbase + jj;
        if (j < KTOP && j > i) {
          float jx1 = sh_box[j][0], jy1 = sh_box[j][1];
          float jx2 = sh_box[j][2], jy2 = sh_box[j][3];
          float iw = fminf(ix2, jx2) - fmaxf(ix1, jx1);
          float ih = fminf(iy2, jy2) - fmaxf(iy1, jy1);
          float inter = fmaxf(iw, 0.0f) * fmaxf(ih, 0.0f);
          float a2 = fmaxf(jx2 - jx1, 0.0f) * fmaxf(jy2 - jy1, 0.0f);
          // iou > 0.65  <=>  inter > 0.65*(a1+a2-inter+1e-9)
          if (inter > 0.65f * (a1 + a2 - inter + 1e-9f)) bits |= (1u << jj);
        }
      }
    }
    sh_mask[i * 16 + w] = bits;
  }
  __syncthreads();

  // ---- Phase F: greedy sequential scan (wave 0); lane l<16 owns suppressed word l
  if (tid < 64) {
    unsigned sup   = (lane < 16) ? sh_inval[lane] : 0u;
    unsigned keepw = 0u;
    unsigned cur = (unsigned)__builtin_amdgcn_readlane((int)sup, 0);
    unsigned mA = (lane < 16) ? sh_mask[0 * 16 + lane] : 0u;
    unsigned mB = (lane < 16) ? sh_mask[1 * 16 + lane] : 0u;
    for (int i = 0; i < KTOP; i += 2) {
      bool ok = ((cur >> (i & 31)) & 1u) == 0u;
      if (ok) {
        sup |= mA;
        if (lane == (i >> 5)) keepw |= (1u << (i & 31));
      }
      cur = (unsigned)__builtin_amdgcn_readlane((int)sup, (i + 1) >> 5);
      mA = (lane < 16 && (i + 2) < KTOP) ? sh_mask[(i + 2) * 16 + lane] : 0u;
      bool ok2 = ((cur >> ((i + 1) & 31)) & 1u) == 0u;
      if (ok2) {
        sup |= mB;
        if (lane == ((i + 1) >> 5)) keepw |= (1u << ((i + 1) & 31));
      }
      cur = (unsigned)__builtin_amdgcn_readlane((int)sup, (i + 2) >> 5);
      mB = (lane < 16 && (i + 3) < KTOP) ? sh_mask[(i + 3) * 16 + lane] : 0u;
    }
    if (lane < 16) sh_keep[lane] = keepw;
  }
  __syncthreads();

  // ---- Phase G: write det * keep
  for (int x = tid; x < KTOP * 7; x += 1024) {
    int k = x / 7, c = x - k * 7;
    float keepf = ((sh_keep[k >> 5] >> (k & 31)) & 1u) ? 1.0f : 0.0f;
    out[(size_t)b * (KTOP * 7) + x] = sh_det[k][c] * keepf;
  }
}

extern "C" void kernel_launch(void* const* d_in, const int* in_sizes, int n_in,
                              void* d_out, int out_size, void* d_ws, size_t ws_size,
                              hipStream_t stream) {
  const float* p8  = (const float*)d_in[0];
  const float* p16 = (const float*)d_in[1];
  const float* p32 = (const float*)d_in[2];
  float* out = (float*)d_out;
  unsigned* hist2 = (unsigned*)d_ws;          // [8][1024]
  unsigned* keys  = hist2 + 8 * NGRP;         // [8][33600]
  hipMemsetAsync(d_ws, 0, (size_t)8 * NGRP * 4, stream);
  k_score<<<dim3((NPI / 2 + 255) / 256, 8), 256, 0, stream>>>(p8, p16, p32, hist2, keys);
  k_post<<<dim3(8), 1024, 0, stream>>>(p8, p16, p32, hist2, keys, out);
}

// Round 3
// 238.477 us; speedup vs baseline: 2.0946x; 1.1199x over previous
//
#include <hip/hip_runtime.h>

#define NPI    33600     // anchors per image: 160^2 + 80^2 + 40^2
#define KTOP   500
#define CAP    1024
#define KEY001 0xBC23D70Au   // monotonic key of 0.01f
#define NGRP   1024
#define NIMG   8

__device__ __forceinline__ float sigmoidf_(float x) {
  return 1.0f / (1.0f + expf(-x));
}
// monotonic float -> u32 key (order-preserving for all non-NaN floats)
__device__ __forceinline__ unsigned fkey(float f) {
  unsigned u = __float_as_uint(f);
  return (u & 0x80000000u) ? ~u : (u | 0x80000000u);
}

// ---------------- Kernel 1: streaming full decode + score key ----------------
// 1 anchor/thread, 16-deep load batches; writes SoA det planes (coalesced).
__global__ __launch_bounds__(256) void k_decode(
    const float* __restrict__ p8, const float* __restrict__ p16,
    const float* __restrict__ p32,
    unsigned* __restrict__ keys, float* __restrict__ dets)
{
  const int b = blockIdx.y;
  const int a = blockIdx.x * 256 + threadIdx.x;
  if (a >= NPI) return;
  const float* lvl; int j, W, HW, S;
  if (a < 25600)      { lvl = p8;  j = a;         W = 160; HW = 25600; S = 8;  }
  else if (a < 32000) { lvl = p16; j = a - 25600; W = 80;  HW = 6400;  S = 16; }
  else                { lvl = p32; j = a - 32000; W = 40;  HW = 1600;  S = 32; }
  const float* base = lvl + (size_t)b * 85 * HW + j;
  float t0 = base[0];
  float t1 = base[(size_t)1 * HW];
  float t2 = base[(size_t)2 * HW];
  float t3 = base[(size_t)3 * HW];
  float t4 = base[(size_t)4 * HW];
  // exact per-class sigmoid argmax, first occurrence (strict >), 16 loads in flight
  float cc = -1.0f; int lab = 0;
  for (int c0 = 0; c0 < 80; c0 += 16) {
    float r[16];
    #pragma unroll
    for (int u = 0; u < 16; ++u) r[u] = base[(size_t)(5 + c0 + u) * HW];
    #pragma unroll
    for (int u = 0; u < 16; ++u) {
      float s = sigmoidf_(r[u]);
      if (s > cc) { cc = s; lab = c0 + u; }
    }
  }
  float obj = sigmoidf_(t4);
  float tot = obj * cc;                       // == sigmoid(obj)*sigmoid(max raw) bitwise
  unsigned key = fkey(tot >= 0.01f ? tot : -1.0f);
  keys[(size_t)b * NPI + a] = key;
  int gy = j / W, gx = j - gy * W;
  float fs = (float)S;
  float cx = (t0 + (float)gx) * fs;
  float cy = (t1 + (float)gy) * fs;
  float w  = expf(t2) * fs;
  float h  = expf(t3) * fs;
  const size_t P  = (size_t)NIMG * NPI;
  const size_t pa = (size_t)b * NPI + a;
  dets[0 * P + pa] = cx - 0.5f * w;
  dets[1 * P + pa] = cy - 0.5f * h;
  dets[2 * P + pa] = cx + 0.5f * w;
  dets[3 * P + pa] = cy + 0.5f * h;
  dets[4 * P + pa] = obj;
  dets[5 * P + pa] = cc;
  dets[6 * P + pa] = (float)lab;
}

// ---------------- Kernel 2: per-image top-500 selection ----------------
__global__ __launch_bounds__(1024) void k_select(
    const unsigned* __restrict__ keys, const float* __restrict__ dets,
    float* __restrict__ topdet, float* __restrict__ boxoff,
    unsigned* __restrict__ invalg)
{
  const int b    = blockIdx.x;
  const int tid  = threadIdx.x;
  const int lane = tid & 63;
  const int wave = tid >> 6;

  __shared__ unsigned lh[NGRP];          // 4 KB coarse hist
  __shared__ unsigned sh_sub[4096];      // 16 KB refine hist
  __shared__ unsigned sh_c64[64];
  __shared__ unsigned sh_G, sh_Chi10, sh_T, sh_Chi, sh_nA, sh_nB;
  __shared__ unsigned long long sh_cand[CAP];
  __shared__ float sh_det[KTOP][7];
  __shared__ float sh_box[KTOP][4];
  __shared__ unsigned sh_inval[16];
  __shared__ unsigned sh_wcA[16], sh_wcB[16];
  __shared__ float sh_red[16];
  __shared__ float sh_maxc;

  for (int i = tid; i < NGRP; i += 1024) lh[i] = 0;
  for (int i = tid; i < 4096; i += 1024) sh_sub[i] = 0;
  __syncthreads();

  const unsigned* kb = keys + (size_t)b * NPI;

  // ---- Pass 1: coarse 1024-bin hist; wave-aggregated (bins are concentrated,
  // plain per-lane LDS atomics would serialize ~40-way)
  for (int k = 0; k < 33; ++k) {
    int i = (k << 10) + tid;
    bool act = (i < NPI);
    unsigned bin = act ? (kb[i] >> 22) : 0xFFFFFFFFu;
    unsigned long long rem = __ballot(act);
    while (rem) {
      int ldr = (int)__builtin_ctzll(rem);
      unsigned lb = (unsigned)__shfl((int)bin, ldr);
      unsigned long long eq = __ballot(act && (bin == lb));
      if (lane == ldr) atomicAdd(&lh[lb], (unsigned)__popcll(eq));
      rem &= ~eq;
    }
  }
  __syncthreads();
  if (tid < 64) {
    unsigned s = 0;
    #pragma unroll
    for (int k = 0; k < 16; ++k) s += lh[tid * 16 + k];
    sh_c64[tid] = s;
  }
  __syncthreads();
  if (tid == 0) {
    unsigned cum = 0; int C = 0;
    for (int g = 63; g >= 0; --g) {
      unsigned v = sh_c64[g];
      if (cum + v >= KTOP) { C = g; break; }
      cum += v;
    }
    int G = C * 16; unsigned chi = cum;
    for (int g = C * 16 + 15; g >= C * 16; --g) {
      unsigned v = lh[g];
      if (chi + v >= KTOP) { G = g; break; }
      chi += v;
    }
    sh_G = (unsigned)G; sh_Chi10 = chi;
    sh_nA = 0; sh_nB = 0;
  }
  __syncthreads();
  const unsigned G = sh_G;

  // ---- Pass 2: 4096-bin sub-hist of bits [21:10] within group G (spread-out,
  // plain atomics fine)
  for (int i = tid; i < NPI; i += 1024) {
    unsigned k = kb[i];
    if ((k >> 22) == G) atomicAdd(&sh_sub[(k >> 10) & 4095u], 1u);
  }
  __syncthreads();
  if (tid < 64) {
    unsigned s = 0;
    for (int k = 0; k < 64; ++k) s += sh_sub[tid * 64 + k];
    sh_c64[tid] = s;
  }
  __syncthreads();
  if (tid == 0) {
    unsigned c = sh_Chi10; int C2 = 0;
    for (int g = 63; g >= 0; --g) {
      unsigned v = sh_c64[g];
      if (c + v >= KTOP) { C2 = g; break; }
      c += v;
    }
    int T12 = C2 * 64;
    for (int t2 = C2 * 64 + 63; t2 >= C2 * 64; --t2) {
      unsigned v = sh_sub[t2];
      if (c + v >= KTOP) { T12 = t2; break; }
      c += v;
    }
    sh_T = (G << 12) | (unsigned)T12;   // 22-bit threshold
    sh_Chi = c;
  }
  __syncthreads();
  const unsigned T = sh_T, Chi = sh_Chi;
  const unsigned Bcap = CAP - Chi;

  // ---- Pass 3: deterministic (index-ordered) compaction
  for (int chunk = 0; chunk < 9; ++chunk) {
    int a0 = chunk * 4096 + tid * 4;
    unsigned kk[4]; bool iA[4], iB[4];
    bool act = (a0 < NPI);
    if (act) {
      uint4 kv = *(const uint4*)(kb + a0);
      kk[0] = kv.x; kk[1] = kv.y; kk[2] = kv.z; kk[3] = kv.w;
    } else { kk[0] = kk[1] = kk[2] = kk[3] = 0u; }
    #pragma unroll
    for (int e = 0; e < 4; ++e) {
      unsigned bin = kk[e] >> 10;
      iA[e] = act && (bin > T);
      iB[e] = act && (bin == T);
    }
    unsigned long long balA[4], balB[4];
    #pragma unroll
    for (int e = 0; e < 4; ++e) { balA[e] = __ballot(iA[e]); balB[e] = __ballot(iB[e]); }
    if (lane == 0) {
      unsigned sA = 0, sB = 0;
      #pragma unroll
      for (int e = 0; e < 4; ++e) { sA += (unsigned)__popcll(balA[e]); sB += (unsigned)__popcll(balB[e]); }
      sh_wcA[wave] = sA; sh_wcB[wave] = sB;
    }
    __syncthreads();
    unsigned pA = sh_nA, pB = sh_nB;
    for (int w2 = 0; w2 < wave; ++w2) { pA += sh_wcA[w2]; pB += sh_wcB[w2]; }
    unsigned long long lt = (1ULL << lane) - 1ULL;
    #pragma unroll
    for (int e = 0; e < 4; ++e) {
      pA += (unsigned)__popcll(balA[e] & lt);
      pB += (unsigned)__popcll(balB[e] & lt);
    }
    #pragma unroll
    for (int e = 0; e < 4; ++e) {
      unsigned long long packed =
          ((unsigned long long)kk[e] << 32) |
          (unsigned long long)(0xFFFFFFFFu - (unsigned)(a0 + e));
      if (iA[e]) { sh_cand[pA] = packed; ++pA; }
      if (iB[e]) { if (pB < Bcap) sh_cand[CAP - 1 - pB] = packed; ++pB; }
    }
    __syncthreads();
    if (tid == 0) {
      unsigned sA = 0, sB = 0;
      for (int w2 = 0; w2 < 16; ++w2) { sA += sh_wcA[w2]; sB += sh_wcB[w2]; }
      sh_nA += sA; sh_nB += sB;
    }
    __syncthreads();
  }
  {
    const unsigned nA  = sh_nA;
    const unsigned nBk = (sh_nB < Bcap) ? sh_nB : Bcap;
    for (int s = (int)nA + tid; s < (int)(CAP - nBk); s += 1024) sh_cand[s] = 0ULL;
  }
  __syncthreads();

  // ---- Bitonic sort 1024 u64 descending ((score desc, index asc))
  for (unsigned kk2 = 2; kk2 <= CAP; kk2 <<= 1) {
    for (unsigned jj = kk2 >> 1; jj > 0; jj >>= 1) {
      unsigned i = (unsigned)tid, p = i ^ jj;
      if (p > i) {
        unsigned long long x = sh_cand[i], y = sh_cand[p];
        bool desc = ((i & kk2) == 0);
        if ((x < y) == desc) { sh_cand[i] = y; sh_cand[p] = x; }
      }
      __syncthreads();
    }
  }

  // ---- Gather top-500 dets from L2-resident planes; max_c; offset boxes; inval bits
  bool validk = false;
  float contrib = -INFINITY;
  if (tid < KTOP) {
    unsigned long long v = sh_cand[tid];
    unsigned keyk = (unsigned)(v >> 32);
    int a = (int)(0xFFFFFFFFu - (unsigned)(v & 0xFFFFFFFFull));
    if (a < 0) a = 0;                 // zero-padded slot (invalid anyway)
    const size_t P  = (size_t)NIMG * NPI;
    const size_t pa = (size_t)b * NPI + (size_t)a;
    float det[7];
    #pragma unroll
    for (int c = 0; c < 7; ++c) det[c] = dets[(size_t)c * P + pa];
    #pragma unroll
    for (int c = 0; c < 7; ++c) sh_det[tid][c] = det[c];
    validk = (keyk >= KEY001);
    float m4 = fmaxf(fmaxf(det[0], det[1]), fmaxf(det[2], det[3]));
    contrib = validk ? m4 : 0.0f;     // jnp.where(valid, boxes, 0) then global max
  }
  float r = contrib;
  #pragma unroll
  for (int off = 32; off > 0; off >>= 1) r = fmaxf(r, __shfl_xor(r, off));
  if (lane == 0) sh_red[wave] = r;
  unsigned long long bv = __ballot((tid < KTOP) && !validk);
  if (wave < 8 && lane == 0) {
    sh_inval[wave * 2]     = (unsigned)(bv & 0xFFFFFFFFull);
    sh_inval[wave * 2 + 1] = (unsigned)(bv >> 32);
  }
  __syncthreads();
  if (tid == 0) {
    float m = -INFINITY;
    for (int w2 = 0; w2 < 16; ++w2) m = fmaxf(m, sh_red[w2]);
    sh_maxc = m + 1.0f;
  }
  __syncthreads();
  const float maxc = sh_maxc;
  if (tid < KTOP) {
    float offb = sh_det[tid][6] * maxc;   // label * max_c
    #pragma unroll
    for (int d = 0; d < 4; ++d) sh_box[tid][d] = sh_det[tid][d] + offb;
  }
  __syncthreads();

  // ---- Export for k_iou / k_nms
  const float* sdet = (const float*)sh_det;
  const float* sbox = (const float*)sh_box;
  for (int x = tid; x < KTOP * 7; x += 1024) topdet[(size_t)b * (KTOP * 7) + x] = sdet[x];
  for (int x = tid; x < KTOP * 4; x += 1024) boxoff[(size_t)b * (KTOP * 4) + x] = sbox[x];
  if (tid < 16) invalg[b * 16 + tid] = sh_inval[tid];
}

// ---------------- Kernel 3: IoU suppression bitmask ----------------
// block = (w-column-group, image); 16 x 8 blocks
__global__ __launch_bounds__(256) void k_iou(
    const float* __restrict__ boxoff, unsigned* __restrict__ gmask)
{
  const int w = blockIdx.x, b = blockIdx.y;
  const int tid = threadIdx.x;
  __shared__ float4 sb[KTOP];
  for (int x = tid; x < KTOP; x += 256)
    sb[x] = ((const float4*)boxoff)[(size_t)b * KTOP + x];
  __syncthreads();
  const int jbase = w * 32;
  for (int i = tid; i < KTOP; i += 256) {
    unsigned bits = 0u;
    if (jbase + 31 > i) {
      float4 bi = sb[i];
      float a1 = fmaxf(bi.z - bi.x, 0.0f) * fmaxf(bi.w - bi.y, 0.0f);
      #pragma unroll 4
      for (int jj = 0; jj < 32; ++jj) {
        int j = jbase + jj;
        if (j < KTOP && j > i) {
          float4 bj = sb[j];              // j uniform across lanes -> LDS broadcast
          float iw = fminf(bi.z, bj.z) - fmaxf(bi.x, bj.x);
          float ih = fminf(bi.w, bj.w) - fmaxf(bi.y, bj.y);
          float inter = fmaxf(iw, 0.0f) * fmaxf(ih, 0.0f);
          float a2 = fmaxf(bj.z - bj.x, 0.0f) * fmaxf(bj.w - bj.y, 0.0f);
          // iou > 0.65  <=>  inter > 0.65*(a1+a2-inter+1e-9)
          if (inter > 0.65f * (a1 + a2 - inter + 1e-9f)) bits |= (1u << jj);
        }
      }
    }
    gmask[((size_t)b * 16 + w) * KTOP + i] = bits;   // [b][w][i], coalesced
  }
}

// ---------------- Kernel 4: greedy scan + final write ----------------
__global__ __launch_bounds__(256) void k_nms(
    const unsigned* __restrict__ gmask, const unsigned* __restrict__ invalg,
    const float* __restrict__ topdet, float* __restrict__ out)
{
  const int b = blockIdx.x;
  const int tid = threadIdx.x;
  const int lane = tid & 63;
  __shared__ unsigned sm[KTOP * 17];     // [i][w], stride 17 -> conflict-free scan reads
  __shared__ unsigned sh_keep[16];
  for (int g = tid; g < KTOP * 16; g += 256) {
    int w = g / KTOP, i = g - w * KTOP;
    sm[i * 17 + w] = gmask[((size_t)b * 16 + w) * KTOP + i];
  }
  __syncthreads();
  if (tid < 64) {
    unsigned sup   = (lane < 16) ? invalg[b * 16 + lane] : 0u;
    unsigned keepw = 0u;
    unsigned cur = (unsigned)__builtin_amdgcn_readlane((int)sup, 0);
    unsigned mA = (lane < 16) ? sm[0 * 17 + lane] : 0u;
    unsigned mB = (lane < 16) ? sm[1 * 17 + lane] : 0u;
    for (int i = 0; i < KTOP; i += 2) {
      bool ok = ((cur >> (i & 31)) & 1u) == 0u;
      if (ok) {
        sup |= mA;
        if (lane == (i >> 5)) keepw |= (1u << (i & 31));
      }
      cur = (unsigned)__builtin_amdgcn_readlane((int)sup, (i + 1) >> 5);
      mA = (lane < 16 && (i + 2) < KTOP) ? sm[(i + 2) * 17 + lane] : 0u;
      bool ok2 = ((cur >> ((i + 1) & 31)) & 1u) == 0u;
      if (ok2) {
        sup |= mB;
        if (lane == ((i + 1) >> 5)) keepw |= (1u << ((i + 1) & 31));
      }
      cur = (unsigned)__builtin_amdgcn_readlane((int)sup, (i + 2) >> 5);
      mB = (lane < 16 && (i + 3) < KTOP) ? sm[(i + 3) * 17 + lane] : 0u;
    }
    if (lane < 16) sh_keep[lane] = keepw;
  }
  __syncthreads();
  for (int x = tid; x < KTOP * 7; x += 256) {
    int k = x / 7;
    float keepf = ((sh_keep[k >> 5] >> (k & 31)) & 1u) ? 1.0f : 0.0f;
    out[(size_t)b * (KTOP * 7) + x] = topdet[(size_t)b * (KTOP * 7) + x] * keepf;
  }
}

extern "C" void kernel_launch(void* const* d_in, const int* in_sizes, int n_in,
                              void* d_out, int out_size, void* d_ws, size_t ws_size,
                              hipStream_t stream) {
  const float* p8  = (const float*)d_in[0];
  const float* p16 = (const float*)d_in[1];
  const float* p32 = (const float*)d_in[2];
  float* out = (float*)d_out;
  // workspace layout (~9.3 MB), fully overwritten every call -> no memset needed
  unsigned* keys   = (unsigned*)d_ws;                        // [8][NPI]
  float*    dets   = (float*)(keys + (size_t)NIMG * NPI);    // [7][8][NPI]
  float*    topdet = dets + (size_t)7 * NIMG * NPI;          // [8][500][7]
  float*    boxoff = topdet + (size_t)NIMG * KTOP * 7;       // [8][500][4] (16B aligned)
  unsigned* invalg = (unsigned*)(boxoff + (size_t)NIMG * KTOP * 4);  // [8][16]
  unsigned* gmask  = invalg + NIMG * 16;                     // [8][16][500]

  k_decode<<<dim3((NPI + 255) / 256, NIMG), 256, 0, stream>>>(p8, p16, p32, keys, dets);
  k_select<<<dim3(NIMG), 1024, 0, stream>>>(keys, dets, topdet, boxoff, invalg);
  k_iou<<<dim3(16, NIMG), 256, 0, stream>>>(boxoff, gmask);
  k_nms<<<dim3(NIMG), 256, 0, stream>>>(gmask, invalg, topdet, out);
}